// Round 1
// baseline (17198.529 us; speedup 1.0000x reference)
//
#include <hip/hip_runtime.h>

#define SEQ   2048
#define BATCH 64
#define HID   256
#define SB    (BATCH * HID)   // 16384 elements per (B,H) slab

typedef __bf16 bf16x8 __attribute__((ext_vector_type(8)));
typedef float  floatx4 __attribute__((ext_vector_type(4)));

__device__ __forceinline__ bf16x8 cvt8(const float* __restrict__ p) {
    float4 lo = *(const float4*)p;
    float4 hi = *(const float4*)(p + 4);
    bf16x8 f;
    f[0] = (__bf16)lo.x; f[1] = (__bf16)lo.y; f[2] = (__bf16)lo.z; f[3] = (__bf16)lo.w;
    f[4] = (__bf16)hi.x; f[5] = (__bf16)hi.y; f[6] = (__bf16)hi.z; f[7] = (__bf16)hi.w;
    return f;
}

__device__ __forceinline__ float sigf(float x) {
    return __builtin_amdgcn_rcpf(1.f + __expf(-x));
}
__device__ __forceinline__ float tanh_fast(float x) {
    // 1 - 2/(1+e^{2x}); saturates correctly at +/-inf
    return 1.f - 2.f * __builtin_amdgcn_rcpf(1.f + __expf(2.f * x));
}

// ws layout: [0, 2*SB floats) = hstage double buffer, then 16 ints of done flags
__global__ void lstm_prep(const float* __restrict__ h0,
                          float* __restrict__ hstage, int* __restrict__ done) {
    int idx = blockIdx.x * blockDim.x + threadIdx.x;
    if (idx < SB) hstage[SB + idx] = h0[idx];   // buffer 1 holds h_{-1} = h0
    if (idx < 16) done[idx] = 0;
}

// 16 blocks x 256 threads. Block b owns h-columns [16b, 16b+16) for all 4 gates.
// Wave w (global wid 0..63): mt = wid&3 (batch tile), nh = wid>>2 (= blockIdx).
__global__ __launch_bounds__(256, 1)
void lstm_persist(const float* __restrict__ x,  const float* __restrict__ c0,
                  const float* __restrict__ Wi, const float* __restrict__ bi,
                  const float* __restrict__ Wh, const float* __restrict__ bh,
                  float* __restrict__ out, float* __restrict__ hstage,
                  int* __restrict__ done) {
    const int tid  = threadIdx.x;
    const int lane = tid & 63;
    const int widx = tid >> 6;                 // 0..3
    const int wid  = blockIdx.x * 4 + widx;    // 0..63
    const int mt   = wid & 3;                  // m-tile (batch rows mt*16..+16)
    const int nh   = wid >> 2;                 // 0..15 == blockIdx.x
    const int q    = lane >> 4;                // 0..3 (k-quad)
    const int c16  = lane & 15;

    // ---- one-time: weight B-fragments into VGPRs (fp32 -> bf16, RNE) ----
    // B-frag for 16x16x32: n = lane&15 (gate column), k = q*8 + j
    bf16x8 wB[2][4][8];
    #pragma unroll
    for (int s = 0; s < 2; ++s) {
        const float* W = s ? Wh : Wi;
        #pragma unroll
        for (int g = 0; g < 4; ++g) {
            const int j = g * HID + nh * 16 + c16;       // W row = gate column
            #pragma unroll
            for (int kt = 0; kt < 8; ++kt)
                wB[s][g][kt] = cvt8(W + j * 256 + kt * 32 + q * 8);
        }
    }

    // bias per lane (same column for all 4 of this lane's cells)
    float bias[4];
    #pragma unroll
    for (int g = 0; g < 4; ++g) {
        const int j = g * HID + nh * 16 + c16;
        bias[g] = bi[j] + bh[j];
    }

    // cell state lives in registers: cells (b = mt*16 + q*4 + r, hcol)
    const int hcol  = nh * 16 + c16;
    const int brow0 = mt * 16 + q * 4;
    float c_st[4];
    #pragma unroll
    for (int r = 0; r < 4; ++r) c_st[r] = c0[(brow0 + r) * HID + hcol];

    const int arow = mt * 16 + c16;   // A-frag row: m = lane&15

    for (int t = 0; t < SEQ; ++t) {
        // ---- x-half: no cross-block dependency; do it before the spin ----
        const float* xt = x + (size_t)t * SB + (size_t)arow * 256;
        bf16x8 ax[8];
        #pragma unroll
        for (int kt = 0; kt < 8; ++kt)
            ax[kt] = cvt8(xt + kt * 32 + q * 8);

        floatx4 acc[4];
        #pragma unroll
        for (int g = 0; g < 4; ++g) acc[g] = (floatx4){0.f, 0.f, 0.f, 0.f};

        #pragma unroll
        for (int kt = 0; kt < 8; ++kt)
            #pragma unroll
            for (int g = 0; g < 4; ++g)
                acc[g] = __builtin_amdgcn_mfma_f32_16x16x32_bf16(
                    ax[kt], wB[0][g][kt], acc[g], 0, 0, 0);

        // ---- wait for h_{t-1} (done[i] >= t means block i published h_{t-1}) ----
        if (t > 0) {
            while (true) {
                int v = __hip_atomic_load(&done[lane & 15], __ATOMIC_RELAXED,
                                          __HIP_MEMORY_SCOPE_AGENT);
                if (__all(v >= t)) break;
                __builtin_amdgcn_s_sleep(1);
            }
            __builtin_amdgcn_fence(__ATOMIC_ACQUIRE, "agent");
        }

        // ---- h-half ----
        const float* hr = hstage + (size_t)(((t + 1) & 1)) * SB + (size_t)arow * 256;
        #pragma unroll
        for (int kt = 0; kt < 8; ++kt) {
            bf16x8 ah = cvt8(hr + kt * 32 + q * 8);
            #pragma unroll
            for (int g = 0; g < 4; ++g)
                acc[g] = __builtin_amdgcn_mfma_f32_16x16x32_bf16(
                    ah, wB[1][g][kt], acc[g], 0, 0, 0);
        }

        // ---- epilogue: gates, state update, stores ----
        float* hw = hstage + (size_t)(t & 1) * SB;
        #pragma unroll
        for (int r = 0; r < 4; ++r) {
            float it = sigf(acc[0][r] + bias[0]);
            float ft = sigf(acc[1][r] + bias[1]);
            float ot = sigf(acc[2][r] + bias[2]);
            float gt = tanh_fast(acc[3][r] + bias[3]);
            float cn = c_st[r] * ft + it * gt;
            c_st[r] = cn;
            float ht = ot * tanh_fast(cn);

            const int b = brow0 + r;
            out[(size_t)t * SB + (size_t)b * HID + hcol] = ht;        // ys (fp32, unrounded)
            // write-through to coherent point so other XCDs can read without our L2 flushing
            __hip_atomic_store(&hw[b * HID + hcol], ht, __ATOMIC_RELAXED,
                               __HIP_MEMORY_SCOPE_AGENT);
            if (t == SEQ - 1) {
                out[(size_t)SEQ * SB + (size_t)b * HID + hcol] = ht;          // h_n
                out[(size_t)SEQ * SB + SB + (size_t)b * HID + hcol] = cn;     // c_n
            }
        }

        // ---- publish: __syncthreads drains vmcnt(0) for ALL waves' stores ----
        __syncthreads();
        if (tid == 0)
            __hip_atomic_store(&done[blockIdx.x], t + 1, __ATOMIC_RELAXED,
                               __HIP_MEMORY_SCOPE_AGENT);
    }
}

extern "C" void kernel_launch(void* const* d_in, const int* in_sizes, int n_in,
                              void* d_out, int out_size, void* d_ws, size_t ws_size,
                              hipStream_t stream) {
    const float* x  = (const float*)d_in[0];
    const float* h0 = (const float*)d_in[1];
    const float* c0 = (const float*)d_in[2];
    const float* Wi = (const float*)d_in[3];
    const float* bi = (const float*)d_in[4];
    const float* Wh = (const float*)d_in[5];
    const float* bh = (const float*)d_in[6];
    float* out = (float*)d_out;

    float* hstage = (float*)d_ws;                                  // 2*SB floats
    int*   done   = (int*)((char*)d_ws + 2 * SB * sizeof(float));  // 16 ints

    lstm_prep<<<64, 256, 0, stream>>>(h0, hstage, done);
    lstm_persist<<<16, 256, 0, stream>>>(x, c0, Wi, bi, Wh, bh, out, hstage, done);
}

// Round 3
// 12065.959 us; speedup vs baseline: 1.4254x; 1.4254x over previous
//
#include <hip/hip_runtime.h>

#define SEQ   2048
#define BATCH 64
#define HID   256
#define SB    (BATCH * HID)   // 16384 elements per (B,H) slab

typedef __bf16  bf16x8  __attribute__((ext_vector_type(8)));
typedef float   floatx4 __attribute__((ext_vector_type(4)));

// ws layout (bytes):
//   [0, 65536)   : __bf16 hstage[2][SB] double buffer
//   [65536, +4)  : int ctr      aggregated step counter (device-scope atomics)
//   [65600, +64) : int cnt[16]  per-XCD registration counters
//   [65664, +4)  : int winner   winning XCD id (-1 until claimed)
#define WS_CTR    65536
#define WS_CNT    65600
#define WS_WINNER 65664

__device__ __forceinline__ bf16x8 cvt8(const float* __restrict__ p) {
    float4 lo = *(const float4*)p;
    float4 hi = *(const float4*)(p + 4);
    bf16x8 f;
    f[0] = (__bf16)lo.x; f[1] = (__bf16)lo.y; f[2] = (__bf16)lo.z; f[3] = (__bf16)lo.w;
    f[4] = (__bf16)hi.x; f[5] = (__bf16)hi.y; f[6] = (__bf16)hi.z; f[7] = (__bf16)hi.w;
    return f;
}

__device__ __forceinline__ float sigf(float x) {
    return __builtin_amdgcn_rcpf(1.f + __expf(-x));
}
__device__ __forceinline__ float tanh_fast(float x) {
    return 1.f - 2.f * __builtin_amdgcn_rcpf(1.f + __expf(2.f * x));
}

// h A-fragment: 8x 16B loads, sc0 = bypass L1, serve from the shared per-XCD L2.
__device__ __forceinline__ void load_h8_l2(const __bf16* p, bf16x8* f) {
    asm volatile(
        "global_load_dwordx4 %0, %8, off sc0\n\t"
        "global_load_dwordx4 %1, %8, off offset:64 sc0\n\t"
        "global_load_dwordx4 %2, %8, off offset:128 sc0\n\t"
        "global_load_dwordx4 %3, %8, off offset:192 sc0\n\t"
        "global_load_dwordx4 %4, %8, off offset:256 sc0\n\t"
        "global_load_dwordx4 %5, %8, off offset:320 sc0\n\t"
        "global_load_dwordx4 %6, %8, off offset:384 sc0\n\t"
        "global_load_dwordx4 %7, %8, off offset:448 sc0\n\t"
        "s_waitcnt vmcnt(0)"
        : "=&v"(f[0]), "=&v"(f[1]), "=&v"(f[2]), "=&v"(f[3]),
          "=&v"(f[4]), "=&v"(f[5]), "=&v"(f[6]), "=&v"(f[7])
        : "v"(p) : "memory");
}

__device__ __forceinline__ int xcc_id() {
    int x;
    asm volatile("s_getreg_b32 %0, hwreg(HW_REG_XCC_ID)" : "=s"(x));
    return x & 0xf;
}

__global__ void lstm_prep(const float* __restrict__ h0, void* __restrict__ ws) {
    int gid = blockIdx.x * blockDim.x + threadIdx.x;
    __bf16* hs = (__bf16*)ws;
    if (gid < SB) hs[SB + gid] = (__bf16)h0[gid];   // buffer 1 holds h_{-1} = h0
    int* ctr = (int*)((char*)ws + WS_CTR);
    int* cnt = (int*)((char*)ws + WS_CNT);
    int* win = (int*)((char*)ws + WS_WINNER);
    if (gid == 0) { *ctr = 0; *win = -1; }
    if (gid < 16) cnt[gid] = 0;
}

// 256 blocks launched; first 16 to register on one XCD do the work through that
// XCD's coherent L2. Block role r: mt = r&3; wave w owns h-cols of tile
// nh = (r>>2)*4 + w, all 4 gates.
__global__ __launch_bounds__(256, 1)
void lstm_persist(const float* __restrict__ x,  const float* __restrict__ c0,
                  const float* __restrict__ Wi, const float* __restrict__ bi,
                  const float* __restrict__ Wh, const float* __restrict__ bh,
                  float* __restrict__ out, void* __restrict__ ws) {
    __bf16* hs  = (__bf16*)ws;
    int* ctr    = (int*)((char*)ws + WS_CTR);
    int* cnt    = (int*)((char*)ws + WS_CNT);
    int* winner = (int*)((char*)ws + WS_WINNER);

    // ---- runtime co-location: claim a role on the winning XCD ----
    __shared__ int s_role;
    if (threadIdx.x == 0) {
        int xcc = xcc_id();
        int r = atomicAdd(&cnt[xcc], 1);             // device-scope, coherent point
        if (r == 15) atomicCAS(winner, -1, xcc);     // 16th member claims the XCD
        int w;
        do {
            w = __hip_atomic_load(winner, __ATOMIC_RELAXED, __HIP_MEMORY_SCOPE_AGENT);
        } while (w < 0);
        s_role = (w == xcc && r < 16) ? r : -1;
    }
    __syncthreads();
    const int role = s_role;
    if (role < 0) return;

    const int tid  = threadIdx.x;
    const int lane = tid & 63;
    const int widx = tid >> 6;
    const int mt   = role & 3;                  // batch m-tile (shared by block)
    const int nh   = (role >> 2) * 4 + widx;    // h-col tile 0..15
    const int q    = lane >> 4;
    const int c16  = lane & 15;

    // ---- one-time: weight B-fragments into registers (fp32 -> bf16 RNE) ----
    bf16x8 wB[2][4][8];
    #pragma unroll
    for (int s = 0; s < 2; ++s) {
        const float* W = s ? Wh : Wi;
        #pragma unroll
        for (int g = 0; g < 4; ++g) {
            const int j = g * HID + nh * 16 + c16;
            #pragma unroll
            for (int kt = 0; kt < 8; ++kt)
                wB[s][g][kt] = cvt8(W + j * 256 + kt * 32 + q * 8);
        }
    }
    float bias[4];
    #pragma unroll
    for (int g = 0; g < 4; ++g) {
        const int j = g * HID + nh * 16 + c16;
        bias[g] = bi[j] + bh[j];
    }

    const int hcol  = nh * 16 + c16;
    const int brow0 = mt * 16 + q * 4;
    const int arow  = mt * 16 + c16;
    float c_st[4];
    #pragma unroll
    for (int r = 0; r < 4; ++r) c_st[r] = c0[(brow0 + r) * HID + hcol];

    floatx4 acc[4];
    // ---- x-half for t=0 (bias folded into acc init) ----
    {
        #pragma unroll
        for (int g = 0; g < 4; ++g)
            acc[g] = (floatx4){bias[g], bias[g], bias[g], bias[g]};
        const float* xt = x + (size_t)arow * 256 + q * 8;
        #pragma unroll
        for (int kt = 0; kt < 8; ++kt) {
            bf16x8 a = cvt8(xt + kt * 32);
            #pragma unroll
            for (int g = 0; g < 4; ++g)
                acc[g] = __builtin_amdgcn_mfma_f32_16x16x32_bf16(a, wB[0][g][kt], acc[g], 0, 0, 0);
        }
    }

    for (int t = 0; t < SEQ; ++t) {
        // ---- wait: all 64 waves published h_{t-1} ----
        if (t > 0) {
            const int need = t * 64;
            int v;
            do {
                v = __hip_atomic_load(ctr, __ATOMIC_RELAXED, __HIP_MEMORY_SCOPE_AGENT);
            } while (__any(v < need));
        }

        // ---- h-half: bf16 A-frags straight from the shared L2 ----
        const __bf16* hr = hs + (size_t)((t + 1) & 1) * SB + (size_t)arow * 256 + q * 8;
        bf16x8 hb[8];
        load_h8_l2(hr, hb);
        #pragma unroll
        for (int kt = 0; kt < 8; ++kt)
            #pragma unroll
            for (int g = 0; g < 4; ++g)
                acc[g] = __builtin_amdgcn_mfma_f32_16x16x32_bf16(hb[kt], wB[1][g][kt], acc[g], 0, 0, 0);

        // ---- epilogue: gates, state update, publish h ----
        __bf16* hw = hs + (size_t)(t & 1) * SB;
        float htv[4], cnv[4];
        #pragma unroll
        for (int r = 0; r < 4; ++r) {
            float it = sigf(acc[0][r]);
            float ft = sigf(acc[1][r]);
            float ot = sigf(acc[2][r]);
            float gt = tanh_fast(acc[3][r]);
            float cn = c_st[r] * ft + it * gt;
            c_st[r] = cn;
            float ht = ot * tanh_fast(cn);
            htv[r] = ht; cnv[r] = cn;
            hw[(brow0 + r) * HID + hcol] = (__bf16)ht;   // write-through L1 -> local L2
        }
        asm volatile("s_waitcnt vmcnt(0)" ::: "memory");  // h acked at L2
        __hip_atomic_fetch_add(ctr, 1, __ATOMIC_RELAXED, __HIP_MEMORY_SCOPE_AGENT);

        // ---- off-critical-path: ys stores, then x-half for t+1 ----
        #pragma unroll
        for (int r = 0; r < 4; ++r)
            out[(size_t)t * SB + (size_t)(brow0 + r) * HID + hcol] = htv[r];
        if (t == SEQ - 1) {
            #pragma unroll
            for (int r = 0; r < 4; ++r) {
                out[(size_t)SEQ * SB + (size_t)(brow0 + r) * HID + hcol] = htv[r];       // h_n
                out[(size_t)SEQ * SB + SB + (size_t)(brow0 + r) * HID + hcol] = cnv[r];  // c_n
            }
        } else {
            #pragma unroll
            for (int g = 0; g < 4; ++g)
                acc[g] = (floatx4){bias[g], bias[g], bias[g], bias[g]};
            const float* xt = x + (size_t)(t + 1) * SB + (size_t)arow * 256 + q * 8;
            #pragma unroll
            for (int kt = 0; kt < 8; ++kt) {
                bf16x8 a = cvt8(xt + kt * 32);
                #pragma unroll
                for (int g = 0; g < 4; ++g)
                    acc[g] = __builtin_amdgcn_mfma_f32_16x16x32_bf16(a, wB[0][g][kt], acc[g], 0, 0, 0);
            }
        }
    }
}

extern "C" void kernel_launch(void* const* d_in, const int* in_sizes, int n_in,
                              void* d_out, int out_size, void* d_ws, size_t ws_size,
                              hipStream_t stream) {
    const float* x  = (const float*)d_in[0];
    const float* h0 = (const float*)d_in[1];
    const float* c0 = (const float*)d_in[2];
    const float* Wi = (const float*)d_in[3];
    const float* bi = (const float*)d_in[4];
    const float* Wh = (const float*)d_in[5];
    const float* bh = (const float*)d_in[6];
    float* out = (float*)d_out;

    lstm_prep<<<64, 256, 0, stream>>>(h0, d_ws);
    lstm_persist<<<256, 256, 0, stream>>>(x, c0, Wi, bi, Wh, bh, out, d_ws);
}